// Round 1
// baseline (587.121 us; speedup 1.0000x reference)
//
#include <hip/hip_runtime.h>

#define F_IN 500
#define HDIM 64
#define CDIM 10
#define KPAD 512           // K padded to 16 MFMA stages of 32
#define NSTAGE 16
#define H2LD 16            // padded h2s row stride (64 B lines)

typedef __attribute__((ext_vector_type(8))) short bf16x8;
typedef __attribute__((ext_vector_type(4))) float floatx4;

// RNE fp32 -> bf16 bits
__device__ inline unsigned short f2bf(float f) {
    unsigned int u = __float_as_uint(f);
    u += 0x7fffu + ((u >> 16) & 1u);
    return (unsigned short)(u >> 16);
}
__device__ inline float bflo(unsigned int u) { return __uint_as_float(u << 16); }
__device__ inline float bfhi(unsigned int u) { return __uint_as_float(u & 0xffff0000u); }

// split 8 fp32 (two float4) into truncated-bf16 hi + residual-bf16 lo
__device__ inline void split8(float4 a, float4 b, bf16x8& xh, bf16x8& xl) {
    float xv[8] = {a.x, a.y, a.z, a.w, b.x, b.y, b.z, b.w};
#pragma unroll
    for (int j = 0; j < 8; ++j) {
        unsigned int u = __float_as_uint(xv[j]);
        xh[j] = (short)(u >> 16);
        float r = xv[j] - __uint_as_float(u & 0xffff0000u);
        xl[j] = (short)(__float_as_uint(r) >> 16);
    }
}

// ---------------------------------------------------------------------------
// Fused Stage 1: blocks [0, degB): in-degree histogram; the returned old
// value IS the edge's rank within its dst row -> erank.  Blocks [degB, ..):
// W1 split into trunc-bf16 hi + residual in MFMA B-fragment order.
// ---------------------------------------------------------------------------
__global__ __launch_bounds__(256) void prep_kernel(
        const int* __restrict__ dst, int E, int* __restrict__ deg,
        int* __restrict__ erank,
        const float* __restrict__ W1, unsigned short* __restrict__ whf,
        unsigned short* __restrict__ wlf, int degB) {
    int bid = blockIdx.x;
    if (bid < degB) {
        int e = bid * 256 + threadIdx.x;
        if (e < E) erank[e] = atomicAdd(&deg[dst[e]], 1);
    } else {
        int idx = (bid - degB) * 256 + threadIdx.x;  // over KPAD*HDIM
        if (idx >= KPAD * HDIM) return;
        int k = idx >> 6;
        int f = idx & 63;
        float w = (k < F_IN) ? W1[k * HDIM + f] : 0.f;
        unsigned int b = __float_as_uint(w);
        unsigned short hh = (unsigned short)(b >> 16);
        float wl = w - __uint_as_float(b & 0xffff0000u);
        unsigned short ll = (unsigned short)(__float_as_uint(wl) >> 16);
        int kb = k >> 5, q = (k >> 3) & 3, j = k & 7;
        int fb = f >> 4, fl = f & 15;
        int lane = (q << 4) | fl;
        size_t o = ((((size_t)kb * 4 + fb) * 64 + lane) << 3) | (size_t)j;
        whf[o] = hh;
        wlf[o] = ll;
    }
}

// ---------------------------------------------------------------------------
// Stage 2: per-block exclusive scan deg -> row_ptr partials; dis fused.
// ---------------------------------------------------------------------------
__global__ void scan_block_kernel(const int* __restrict__ deg,
                                  int* __restrict__ row_ptr,
                                  int* __restrict__ blk_sum,
                                  float* __restrict__ dis, int Np1) {
    __shared__ int wsum[16];
    int i = blockIdx.x * 1024 + threadIdx.x;
    int v = (i < Np1 - 1) ? deg[i] : 0;
    if (i < Np1 - 1) dis[i] = rsqrtf((float)(v + 1));
    int lane = threadIdx.x & 63;
    int wid = threadIdx.x >> 6;
    int x = v;
#pragma unroll
    for (int off = 1; off < 64; off <<= 1) {
        int y = __shfl_up(x, off);
        if (lane >= off) x += y;
    }
    if (lane == 63) wsum[wid] = x;
    __syncthreads();
    if (threadIdx.x < 16) {
        int ws = wsum[threadIdx.x];
#pragma unroll
        for (int off = 1; off < 16; off <<= 1) {
            int y = __shfl_up(ws, off);
            if ((int)threadIdx.x >= off) ws += y;
        }
        wsum[threadIdx.x] = ws;
    }
    __syncthreads();
    int wp = (wid > 0) ? wsum[wid - 1] : 0;
    if (i < Np1) row_ptr[i] = wp + x - v;
    if (threadIdx.x == 1023) blk_sum[blockIdx.x] = wp + x;
}

__global__ void scan_top_kernel(int* __restrict__ blk_sum, int nb) {
    int carry = 0;
    for (int base = 0; base < nb; base += 64) {
        int i = base + (int)threadIdx.x;
        int v = (i < nb) ? blk_sum[i] : 0;
        int x = v;
#pragma unroll
        for (int off = 1; off < 64; off <<= 1) {
            int y = __shfl_up(x, off);
            if ((int)threadIdx.x >= off) x += y;
        }
        if (i < nb) blk_sum[i] = carry + x - v;
        carry += __shfl(x, 63);
    }
}

// ---------------------------------------------------------------------------
// Fused Stage 3+4, INTERLEAVED: every 5th block runs the MFMA GEMM (16 rows
// per wave, 6250 gemm waves); others run the atomic-free CSR scatter.
// GEMM K-loop: FIFO-safe issue order.  Per stage kb we issue
//   [w(kb+1) fragments]  then  [x(kb+3) row chunks]
// so the s_waitcnt for w(kb) (issued one stage back, L2-hot) never forces
// an x load younger than 2 stages, and the wait for x(kb) hits the oldest
// queue entry (3 stages old ~ HBM latency covered).
// ---------------------------------------------------------------------------
__global__ __launch_bounds__(256) void csr_gemm_kernel(
        // gemm args
        const float* __restrict__ x, const unsigned short* __restrict__ whf,
        const unsigned short* __restrict__ wlf, const float* __restrict__ dis,
        unsigned short* __restrict__ h1b, int N,
        // csr args
        const int* __restrict__ src, const int* __restrict__ dst,
        const int* __restrict__ erank,
        const int* __restrict__ row_ptr, const int* __restrict__ blk_sum,
        int* __restrict__ csr_src, int E,
        int gemmB) {
    const int bid = blockIdx.x;
    const int g5 = bid / 5;
    const bool isGemm = (bid % 5 == 0) && (g5 < gemmB);
    if (!isGemm) {
        // ----- CSR fill path (no atomics: rank precomputed in prep) -----
        int before = (bid + 4) / 5;          // gemm blocks preceding bid
        if (before > gemmB) before = gemmB;
        int cb = bid - before;
        int e = cb * 256 + threadIdx.x;
        if (e >= E) return;
        int d = dst[e];
        csr_src[row_ptr[d] + blk_sum[d >> 10] + erank[e]] = src[e];
        return;
    }
    // ----- GEMM path: 16 rows per wave -----
    const int lane = threadIdx.x & 63;
    const int wid = (g5 << 2) + (threadIdx.x >> 6);
    const int n0 = wid * 16;
    if (n0 >= N) return;
    const int q = lane >> 4;
    const int fl = lane & 15;
    const float* xp = x + (size_t)(n0 + fl) * F_IN + q * 8;

    const bf16x8* whv = (const bf16x8*)whf;
    const bf16x8* wlv = (const bf16x8*)wlf;

    floatx4 acc[4];
#pragma unroll
    for (int fb = 0; fb < 4; ++fb) acc[fb] = (floatx4){0.f, 0.f, 0.f, 0.f};

    // register pipeline buffers: x 4-deep (use + 3 in flight), w 2-deep
    float4 xa[4], xb[4];
    bf16x8 wh[2][4], wl[2][4];

    // prologue: x stages 0..2 first, then w stage 0
    xa[0] = *(const float4*)(xp);
    xb[0] = *(const float4*)(xp + 4);
    xa[1] = *(const float4*)(xp + 32);
    xb[1] = *(const float4*)(xp + 36);
    xa[2] = *(const float4*)(xp + 64);
    xb[2] = *(const float4*)(xp + 68);
#pragma unroll
    for (int fb = 0; fb < 4; ++fb) {
        wh[0][fb] = whv[(size_t)fb * 64 + lane];
        wl[0][fb] = wlv[(size_t)fb * 64 + lane];
    }

#pragma unroll
    for (int kb = 0; kb < NSTAGE - 1; ++kb) {
        const int cw = kb & 1, nw = cw ^ 1;
        // issue w fragments for stage kb+1 (always valid: K padded to 16 stages)
#pragma unroll
        for (int fb = 0; fb < 4; ++fb) {
            wh[nw][fb] = whv[(size_t)((kb + 1) * 4 + fb) * 64 + lane];
            wl[nw][fb] = wlv[(size_t)((kb + 1) * 4 + fb) * 64 + lane];
        }
        // issue x chunk for stage kb+3 (stages 3..14; stage 15 = guarded tail)
        if (kb + 3 < NSTAGE - 1) {
            xa[(kb + 3) & 3] = *(const float4*)(xp + (kb + 3) * 32);
            xb[(kb + 3) & 3] = *(const float4*)(xp + (kb + 3) * 32 + 4);
        }
        // compute stage kb
        bf16x8 xh, xl;
        split8(xa[kb & 3], xb[kb & 3], xh, xl);
#pragma unroll
        for (int fb = 0; fb < 4; ++fb) {
            acc[fb] = __builtin_amdgcn_mfma_f32_16x16x32_bf16(xh, wh[cw][fb], acc[fb], 0, 0, 0);
            acc[fb] = __builtin_amdgcn_mfma_f32_16x16x32_bf16(xl, wh[cw][fb], acc[fb], 0, 0, 0);
            acc[fb] = __builtin_amdgcn_mfma_f32_16x16x32_bf16(xh, wl[cw][fb], acc[fb], 0, 0, 0);
        }
    }
    {   // tail stage kb = 15 (k 480..511, valid k < 500), guarded loads
        const int kb = NSTAGE - 1;
        float xv[8];
#pragma unroll
        for (int j = 0; j < 8; ++j) {
            int kk = kb * 32 + q * 8 + j;
            xv[j] = (kk < F_IN) ? xp[kb * 32 + j] : 0.f;
        }
        bf16x8 xh, xl;
#pragma unroll
        for (int j = 0; j < 8; ++j) {
            unsigned int u = __float_as_uint(xv[j]);
            xh[j] = (short)(u >> 16);
            float r = xv[j] - __uint_as_float(u & 0xffff0000u);
            xl[j] = (short)(__float_as_uint(r) >> 16);
        }
        const int cw = kb & 1;  // = 1, written by iteration kb=14
#pragma unroll
        for (int fb = 0; fb < 4; ++fb) {
            acc[fb] = __builtin_amdgcn_mfma_f32_16x16x32_bf16(xh, wh[cw][fb], acc[fb], 0, 0, 0);
            acc[fb] = __builtin_amdgcn_mfma_f32_16x16x32_bf16(xl, wh[cw][fb], acc[fb], 0, 0, 0);
            acc[fb] = __builtin_amdgcn_mfma_f32_16x16x32_bf16(xh, wl[cw][fb], acc[fb], 0, 0, 0);
        }
    }
    // epilogue: C/D layout row = q*4+r, col = fb*16+fl
#pragma unroll
    for (int r = 0; r < 4; ++r) {
        int node = n0 + q * 4 + r;
        float dn = dis[node];
#pragma unroll
        for (int fb = 0; fb < 4; ++fb) {
            h1b[(size_t)node * HDIM + fb * 16 + fl] = f2bf(acc[fb][r] * dn);
        }
    }
}

// ---------------------------------------------------------------------------
// Stage 5+6 fused: gather layer 1 + layer-2 dense.  h1b rows pre-scaled by
// dis[s] -> pure adds.  Wave per node, half-wave per edge parity, 8 edges in
// flight per half.  After the xor-32 reduce every lane holds the full
// 64-feature row (lane&31 -> features 2c,2c+1), so relu(+b1) and the 64x10
// matvec run in-register with a 5-level shfl reduce; h2s written directly.
// ---------------------------------------------------------------------------
__global__ __launch_bounds__(256) void gather1_l2_kernel(
        const int* __restrict__ row_ptr, const int* __restrict__ blk_sum,
        const int* __restrict__ csr_src, const float* __restrict__ dis,
        const unsigned short* __restrict__ h1b,
        const float* __restrict__ b1, const float* __restrict__ W2,
        float* __restrict__ h2s, int N) {
    __shared__ float sW2[HDIM * CDIM];
    __shared__ float sB1[HDIM];
    for (int i = threadIdx.x; i < HDIM * CDIM; i += 256) sW2[i] = W2[i];
    if (threadIdx.x < HDIM) sB1[threadIdx.x] = b1[threadIdx.x];
    __syncthreads();
    int nid = blockIdx.x * 4 + (threadIdx.x >> 6);
    if (nid >= N) return;
    int node = __builtin_amdgcn_readfirstlane(nid);
    int lane = threadIdx.x & 63;
    int half = lane >> 5;
    int c = lane & 31;  // features 2c, 2c+1
    int beg = row_ptr[node] + blk_sum[node >> 10];
    int end = row_ptr[node + 1] + blk_sum[(node + 1) >> 10];
    float dd = dis[node];
    float a0 = 0.f, a1 = 0.f;
    if (half == 0) {  // self-loop: row already holds h1*dis[node]
        unsigned int w = *reinterpret_cast<const unsigned int*>(
            h1b + (size_t)node * HDIM + 2 * c);
        a0 = bflo(w);
        a1 = bfhi(w);
    }
    int p = beg + half;
    for (; p + 14 < end; p += 16) {  // 8 edges in flight per half
        unsigned int wv[8];
#pragma unroll
        for (int i = 0; i < 8; ++i) {
            int s = csr_src[p + 2 * i];
            wv[i] = *reinterpret_cast<const unsigned int*>(
                h1b + (size_t)s * HDIM + 2 * c);
        }
#pragma unroll
        for (int i = 0; i < 8; ++i) {
            a0 += bflo(wv[i]);
            a1 += bfhi(wv[i]);
        }
    }
    for (; p < end; p += 2) {
        int s0 = csr_src[p];
        unsigned int w0 = *reinterpret_cast<const unsigned int*>(
            h1b + (size_t)s0 * HDIM + 2 * c);
        a0 += bflo(w0);
        a1 += bfhi(w0);
    }
    a0 += __shfl_xor(a0, 32);
    a1 += __shfl_xor(a1, 32);
    // fused layer 2: t = relu(agg*dd + b1); p[j] = t @ W2 (partial, 2 feats)
    float t0 = a0 * dd + sB1[2 * c];
    float t1 = a1 * dd + sB1[2 * c + 1];
    t0 = t0 > 0.f ? t0 : 0.f;
    t1 = t1 > 0.f ? t1 : 0.f;
    float pj[CDIM];
#pragma unroll
    for (int j = 0; j < CDIM; ++j)
        pj[j] = t0 * sW2[(2 * c) * CDIM + j] + t1 * sW2[(2 * c + 1) * CDIM + j];
#pragma unroll
    for (int off = 1; off < 32; off <<= 1) {
#pragma unroll
        for (int j = 0; j < CDIM; ++j) pj[j] += __shfl_xor(pj[j], off);
    }
    if (lane < CDIM) {  // lanes 0..9 (half==0), c==lane
        float v = pj[0];
#pragma unroll
        for (int j = 1; j < CDIM; ++j)
            if (lane == j) v = pj[j];
        h2s[(size_t)node * H2LD + lane] = v * dd;
    }
}

// ---------------------------------------------------------------------------
// Stage 7: gather layer 2.  Wave per node, 4 groups x 16 lanes, 4 edges in
// flight per group; h2s rows 64-B aligned; shfl reduce; bias + self at end.
// ---------------------------------------------------------------------------
__global__ __launch_bounds__(256) void gather2_kernel(
        const int* __restrict__ row_ptr, const int* __restrict__ blk_sum,
        const int* __restrict__ csr_src, const float* __restrict__ dis,
        const float* __restrict__ h2s, const float* __restrict__ b2,
        float* __restrict__ out, int N) {
    int nid = blockIdx.x * 4 + (threadIdx.x >> 6);
    if (nid >= N) return;
    int node = __builtin_amdgcn_readfirstlane(nid);
    int lane = threadIdx.x & 63;
    int g = lane >> 4;
    int j = lane & 15;
    int beg = row_ptr[node] + blk_sum[node >> 10];
    int end = row_ptr[node + 1] + blk_sum[(node + 1) >> 10];
    float acc = 0.f;
    int p = beg + g;
    for (; p + 12 < end; p += 16) {  // 4 edges in flight per group
        int s0 = csr_src[p];
        int s1 = csr_src[p + 4];
        int s2 = csr_src[p + 8];
        int s3 = csr_src[p + 12];
        float v0 = (j < CDIM) ? h2s[(size_t)s0 * H2LD + j] : 0.f;
        float v1 = (j < CDIM) ? h2s[(size_t)s1 * H2LD + j] : 0.f;
        float v2 = (j < CDIM) ? h2s[(size_t)s2 * H2LD + j] : 0.f;
        float v3 = (j < CDIM) ? h2s[(size_t)s3 * H2LD + j] : 0.f;
        acc += (v0 + v1) + (v2 + v3);
    }
    for (; p < end; p += 4) {
        int s0 = csr_src[p];
        acc += (j < CDIM) ? h2s[(size_t)s0 * H2LD + j] : 0.f;
    }
    acc += __shfl_xor(acc, 16);
    acc += __shfl_xor(acc, 32);
    if (lane < CDIM) {
        float dd = dis[node];
        out[(size_t)node * CDIM + lane] =
            b2[lane] + dd * (acc + h2s[(size_t)node * H2LD + lane]);
    }
}

// ---------------------------------------------------------------------------
static inline char* align256(char* p) {
    return (char*)(((uintptr_t)p + 255) & ~(uintptr_t)255);
}

extern "C" void kernel_launch(void* const* d_in, const int* in_sizes, int n_in,
                              void* d_out, int out_size, void* d_ws,
                              size_t ws_size, hipStream_t stream) {
    const float* x  = (const float*)d_in[0];
    const int*   ei = (const int*)d_in[1];
    const float* W1 = (const float*)d_in[2];
    const float* b1 = (const float*)d_in[3];
    const float* W2 = (const float*)d_in[4];
    const float* b2 = (const float*)d_in[5];

    const int N = in_sizes[0] / F_IN;   // 100000
    const int E = in_sizes[1] / 2;      // 1600000
    const int* src = ei;
    const int* dst = ei + E;
    float* out = (float*)d_out;

    const int Np1 = N + 1;
    const int nscan_blocks = (Np1 + 1023) / 1024;

    // workspace layout, 256B-aligned chunks
    char* w = (char*)d_ws;
    int* deg = (int*)w;                  w = align256(w + (size_t)N * 4);  // zeroed
    char* zero_end = w;
    int* erank = (int*)w;                w = align256(w + (size_t)E * 4);
    float* dis = (float*)w;              w = align256(w + (size_t)N * 4);
    int* row_ptr = (int*)w;              w = align256(w + (size_t)(N + 4) * 4);
    int* blk_sum = (int*)w;              w = align256(w + (size_t)nscan_blocks * 4);
    int* csr_src = (int*)w;              w = align256(w + (size_t)E * 4);
    unsigned short* whf = (unsigned short*)w;  w = align256(w + (size_t)KPAD * HDIM * 2);
    unsigned short* wlf = (unsigned short*)w;  w = align256(w + (size_t)KPAD * HDIM * 2);
    unsigned short* h1b = (unsigned short*)w;  w = align256(w + (size_t)N * HDIM * 2);
    float* h2s = (float*)w;              w = align256(w + (size_t)N * H2LD * 4);

    hipMemsetAsync(deg, 0, (size_t)(zero_end - (char*)deg), stream);  // deg only

    const int degB = (E + 255) / 256;                    // 6250
    const int wprepB = (KPAD * HDIM + 255) / 256;        // 128
    prep_kernel<<<degB + wprepB, 256, 0, stream>>>(dst, E, deg, erank, W1, whf,
                                                   wlf, degB);
    scan_block_kernel<<<nscan_blocks, 1024, 0, stream>>>(deg, row_ptr, blk_sum,
                                                         dis, Np1);
    scan_top_kernel<<<1, 64, 0, stream>>>(blk_sum, nscan_blocks);
    {
        int gemmB = ((N + 15) / 16 + 3) / 4;             // 1563
        int csrB = (E + 255) / 256;                      // 6250
        csr_gemm_kernel<<<gemmB + csrB, 256, 0, stream>>>(
            x, whf, wlf, dis, h1b, N,
            src, dst, erank, row_ptr, blk_sum, csr_src, E, gemmB);
    }
    gather1_l2_kernel<<<(N + 3) / 4, 256, 0, stream>>>(row_ptr, blk_sum,
                                                       csr_src, dis, h1b,
                                                       b1, W2, h2s, N);
    gather2_kernel<<<(N + 3) / 4, 256, 0, stream>>>(row_ptr, blk_sum, csr_src,
                                                    dis, h2s, b2, out, N);
}

// Round 2
// 533.510 us; speedup vs baseline: 1.1005x; 1.1005x over previous
//
#include <hip/hip_runtime.h>

#define F_IN 500
#define HDIM 64
#define CDIM 10
#define KPAD 512           // K padded to 16 MFMA stages of 32
#define NSTAGE 16
#define H2LD 16            // padded h2s row stride (64 B lines)
#define BUFSZ 24576        // per pipeline buffer: x 16K + wh 4K + wl 4K

typedef __attribute__((ext_vector_type(8))) short bf16x8;
typedef __attribute__((ext_vector_type(4))) float floatx4;

// RNE fp32 -> bf16 bits
__device__ inline unsigned short f2bf(float f) {
    unsigned int u = __float_as_uint(f);
    u += 0x7fffu + ((u >> 16) & 1u);
    return (unsigned short)(u >> 16);
}
__device__ inline float bflo(unsigned int u) { return __uint_as_float(u << 16); }
__device__ inline float bfhi(unsigned int u) { return __uint_as_float(u & 0xffff0000u); }

// async global->LDS, 16 B per lane; LDS dest is wave-uniform base + lane*16
__device__ inline void gload16(const void* g, void* l) {
    __builtin_amdgcn_global_load_lds(
        (const __attribute__((address_space(1))) void*)g,
        (__attribute__((address_space(3))) void*)l, 16, 0, 0);
}

// split 8 fp32 (two float4) into truncated-bf16 hi + residual-bf16 lo
__device__ inline void split8(float4 a, float4 b, bf16x8& xh, bf16x8& xl) {
    float xv[8] = {a.x, a.y, a.z, a.w, b.x, b.y, b.z, b.w};
#pragma unroll
    for (int j = 0; j < 8; ++j) {
        unsigned int u = __float_as_uint(xv[j]);
        xh[j] = (short)(u >> 16);
        float r = xv[j] - __uint_as_float(u & 0xffff0000u);
        xl[j] = (short)(__float_as_uint(r) >> 16);
    }
}

// ---------------------------------------------------------------------------
// Fused Stage 1: blocks [0, degB): in-degree histogram; the returned old
// value IS the edge's rank within its dst row -> erank.  Blocks [degB, ..):
// W1 split into trunc-bf16 hi + residual in MFMA B-fragment order.
// ---------------------------------------------------------------------------
__global__ __launch_bounds__(256) void prep_kernel(
        const int* __restrict__ dst, int E, int* __restrict__ deg,
        int* __restrict__ erank,
        const float* __restrict__ W1, unsigned short* __restrict__ whf,
        unsigned short* __restrict__ wlf, int degB) {
    int bid = blockIdx.x;
    if (bid < degB) {
        int e = bid * 256 + threadIdx.x;
        if (e < E) erank[e] = atomicAdd(&deg[dst[e]], 1);
    } else {
        int idx = (bid - degB) * 256 + threadIdx.x;  // over KPAD*HDIM
        if (idx >= KPAD * HDIM) return;
        int k = idx >> 6;
        int f = idx & 63;
        float w = (k < F_IN) ? W1[k * HDIM + f] : 0.f;
        unsigned int b = __float_as_uint(w);
        unsigned short hh = (unsigned short)(b >> 16);
        float wl = w - __uint_as_float(b & 0xffff0000u);
        unsigned short ll = (unsigned short)(__float_as_uint(wl) >> 16);
        int kb = k >> 5, q = (k >> 3) & 3, j = k & 7;
        int fb = f >> 4, fl = f & 15;
        int lane = (q << 4) | fl;
        size_t o = ((((size_t)kb * 4 + fb) * 64 + lane) << 3) | (size_t)j;
        whf[o] = hh;
        wlf[o] = ll;
    }
}

// ---------------------------------------------------------------------------
// Stage 2: per-block exclusive scan deg -> row_ptr partials; dis fused.
// ---------------------------------------------------------------------------
__global__ void scan_block_kernel(const int* __restrict__ deg,
                                  int* __restrict__ row_ptr,
                                  int* __restrict__ blk_sum,
                                  float* __restrict__ dis, int Np1) {
    __shared__ int wsum[16];
    int i = blockIdx.x * 1024 + threadIdx.x;
    int v = (i < Np1 - 1) ? deg[i] : 0;
    if (i < Np1 - 1) dis[i] = rsqrtf((float)(v + 1));
    int lane = threadIdx.x & 63;
    int wid = threadIdx.x >> 6;
    int x = v;
#pragma unroll
    for (int off = 1; off < 64; off <<= 1) {
        int y = __shfl_up(x, off);
        if (lane >= off) x += y;
    }
    if (lane == 63) wsum[wid] = x;
    __syncthreads();
    if (threadIdx.x < 16) {
        int ws = wsum[threadIdx.x];
#pragma unroll
        for (int off = 1; off < 16; off <<= 1) {
            int y = __shfl_up(ws, off);
            if ((int)threadIdx.x >= off) ws += y;
        }
        wsum[threadIdx.x] = ws;
    }
    __syncthreads();
    int wp = (wid > 0) ? wsum[wid - 1] : 0;
    if (i < Np1) row_ptr[i] = wp + x - v;
    if (threadIdx.x == 1023) blk_sum[blockIdx.x] = wp + x;
}

__global__ void scan_top_kernel(int* __restrict__ blk_sum, int nb) {
    int carry = 0;
    for (int base = 0; base < nb; base += 64) {
        int i = base + (int)threadIdx.x;
        int v = (i < nb) ? blk_sum[i] : 0;
        int x = v;
#pragma unroll
        for (int off = 1; off < 64; off <<= 1) {
            int y = __shfl_up(x, off);
            if ((int)threadIdx.x >= off) x += y;
        }
        if (i < nb) blk_sum[i] = carry + x - v;
        carry += __shfl(x, 63);
    }
}

// ---------------------------------------------------------------------------
// Fused Stage 3+4, INTERLEAVED: every 9th block runs the LDS-staged MFMA
// GEMM (BM=128 rows, 4 waves x 32 rows); others run the atomic-free CSR
// scatter.  GEMM K-loop: 2-phase double-buffered global_load_lds pipeline
// (stage kb+1 -> compute kb -> barrier).  x tile stored with XOR granule
// swizzle (applied on the per-lane GLOBAL source address; LDS dest linear)
// so ds_read_b128 A-fragments hit the uniform bank floor.
// ---------------------------------------------------------------------------
__global__ __launch_bounds__(256) void csr_gemm_kernel(
        // gemm args
        const float* __restrict__ x, const unsigned short* __restrict__ whf,
        const unsigned short* __restrict__ wlf, const float* __restrict__ dis,
        unsigned short* __restrict__ h1b, int N,
        // csr args
        const int* __restrict__ src, const int* __restrict__ dst,
        const int* __restrict__ erank,
        const int* __restrict__ row_ptr, const int* __restrict__ blk_sum,
        int* __restrict__ csr_src, int E,
        int gemmB) {
    __shared__ float4 shmem[2 * BUFSZ / 16];
    char* sh = (char*)shmem;
    const int bid = blockIdx.x;
    const int g9 = bid / 9;
    const bool isGemm = (bid % 9 == 0) && (g9 < gemmB);
    if (!isGemm) {
        // ----- CSR fill path (no atomics: rank precomputed in prep) -----
        int before = (bid + 8) / 9;          // gemm blocks preceding bid
        if (before > gemmB) before = gemmB;
        int cb = bid - before;
        int e = cb * 256 + threadIdx.x;
        if (e >= E) return;
        int d = dst[e];
        csr_src[row_ptr[d] + blk_sum[d >> 10] + erank[e]] = src[e];
        return;
    }
    // ----- GEMM path: block tile 128 rows, wave handles 32 rows -----
    const int lane = threadIdx.x & 63;
    const int w = threadIdx.x >> 6;       // wave 0..3
    const int n0 = g9 * 128;
    const int q = lane >> 4;
    const int fl = lane & 15;

    floatx4 acc[2][4];
#pragma unroll
    for (int t = 0; t < 2; ++t)
#pragma unroll
        for (int fb = 0; fb < 4; ++fb) acc[t][fb] = (floatx4){0.f, 0.f, 0.f, 0.f};

    // stage one K-step (32 floats/row) into buffer `buf`:
    //   x region [0,16384): row ro at ro*128, granule slot s holds logical
    //   granule s ^ (ro&7)  (swizzle applied via source address)
    //   wh [16384,20480), wl [20480,24576): linear fragment order
    auto STAGE = [&](int buf, int kb) {
        const size_t bb = (size_t)buf * BUFSZ;
#pragma unroll
        for (int r2 = 0; r2 < 4; ++r2) {
            int c = w * 4 + r2;                 // 1 KiB chunk id, 0..15
            int o = c * 1024 + lane * 16;       // LDS byte offset in x region
            int ro = o >> 7;                    // tile row 0..127
            int gl = ((o >> 4) & 7) ^ (ro & 7); // logical granule for this slot
            if (kb == NSTAGE - 1 && gl > 4) gl = 0;  // k>=500 dead (w pad = 0)
            int xrow = n0 + ro;
            if (xrow >= N) xrow = N - 1;        // clamp (results discarded)
            gload16(x + (size_t)xrow * F_IN + kb * 32 + gl * 4,
                    sh + bb + c * 1024);
        }
        gload16((const char*)whf + (size_t)kb * 4096 + w * 1024 + lane * 16,
                sh + bb + 16384 + w * 1024);
        gload16((const char*)wlf + (size_t)kb * 4096 + w * 1024 + lane * 16,
                sh + bb + 20480 + w * 1024);
    };

    STAGE(0, 0);
    __syncthreads();
    int cur = 0;
#pragma unroll
    for (int kb = 0; kb < NSTAGE; ++kb) {
        if (kb + 1 < NSTAGE) STAGE(cur ^ 1, kb + 1);
        const size_t bb = (size_t)cur * BUFSZ;
        bf16x8 bh[4], bl[4];
#pragma unroll
        for (int fb = 0; fb < 4; ++fb) {
            bh[fb] = *(const bf16x8*)(sh + bb + 16384 + fb * 1024 + lane * 16);
            bl[fb] = *(const bf16x8*)(sh + bb + 20480 + fb * 1024 + lane * 16);
        }
#pragma unroll
        for (int t = 0; t < 2; ++t) {
            int tr = w * 32 + t * 16 + fl;      // tile row this lane reads
            int sw = tr & 7;
            float4 a0 = *(const float4*)(sh + bb + tr * 128 + (((2 * q) ^ sw) << 4));
            float4 a1 = *(const float4*)(sh + bb + tr * 128 + (((2 * q + 1) ^ sw) << 4));
            bf16x8 xh, xl;
            split8(a0, a1, xh, xl);
#pragma unroll
            for (int fb = 0; fb < 4; ++fb) {
                acc[t][fb] = __builtin_amdgcn_mfma_f32_16x16x32_bf16(xh, bh[fb], acc[t][fb], 0, 0, 0);
                acc[t][fb] = __builtin_amdgcn_mfma_f32_16x16x32_bf16(xl, bh[fb], acc[t][fb], 0, 0, 0);
                acc[t][fb] = __builtin_amdgcn_mfma_f32_16x16x32_bf16(xh, bl[fb], acc[t][fb], 0, 0, 0);
            }
        }
        __syncthreads();   // drains vmcnt (next stage ready) + lgkm (reads done)
        cur ^= 1;
    }
    // epilogue: C/D layout row = q*4+r, col = fb*16+fl
#pragma unroll
    for (int t = 0; t < 2; ++t) {
#pragma unroll
        for (int r = 0; r < 4; ++r) {
            int node = n0 + w * 32 + t * 16 + q * 4 + r;
            if (node < N) {
                float dn = dis[node];
#pragma unroll
                for (int fb = 0; fb < 4; ++fb) {
                    h1b[(size_t)node * HDIM + fb * 16 + fl] =
                        f2bf(acc[t][fb][r] * dn);
                }
            }
        }
    }
}

// ---------------------------------------------------------------------------
// Stage 5+6 fused: gather layer 1 + layer-2 dense.  h1b rows pre-scaled by
// dis[s] -> pure adds.  Wave per node, half-wave per edge parity, 8 edges in
// flight per half.  After the xor-32 reduce every lane holds the full
// 64-feature row, so relu(+b1) and the 64x10 matvec run in-register with a
// 5-level shfl reduce; h2s written directly.
// ---------------------------------------------------------------------------
__global__ __launch_bounds__(256) void gather1_l2_kernel(
        const int* __restrict__ row_ptr, const int* __restrict__ blk_sum,
        const int* __restrict__ csr_src, const float* __restrict__ dis,
        const unsigned short* __restrict__ h1b,
        const float* __restrict__ b1, const float* __restrict__ W2,
        float* __restrict__ h2s, int N) {
    __shared__ float sW2[HDIM * CDIM];
    __shared__ float sB1[HDIM];
    for (int i = threadIdx.x; i < HDIM * CDIM; i += 256) sW2[i] = W2[i];
    if (threadIdx.x < HDIM) sB1[threadIdx.x] = b1[threadIdx.x];
    __syncthreads();
    int nid = blockIdx.x * 4 + (threadIdx.x >> 6);
    if (nid >= N) return;
    int node = __builtin_amdgcn_readfirstlane(nid);
    int lane = threadIdx.x & 63;
    int half = lane >> 5;
    int c = lane & 31;  // features 2c, 2c+1
    int beg = row_ptr[node] + blk_sum[node >> 10];
    int end = row_ptr[node + 1] + blk_sum[(node + 1) >> 10];
    float dd = dis[node];
    float a0 = 0.f, a1 = 0.f;
    if (half == 0) {  // self-loop: row already holds h1*dis[node]
        unsigned int w = *reinterpret_cast<const unsigned int*>(
            h1b + (size_t)node * HDIM + 2 * c);
        a0 = bflo(w);
        a1 = bfhi(w);
    }
    int p = beg + half;
    for (; p + 14 < end; p += 16) {  // 8 edges in flight per half
        unsigned int wv[8];
#pragma unroll
        for (int i = 0; i < 8; ++i) {
            int s = csr_src[p + 2 * i];
            wv[i] = *reinterpret_cast<const unsigned int*>(
                h1b + (size_t)s * HDIM + 2 * c);
        }
#pragma unroll
        for (int i = 0; i < 8; ++i) {
            a0 += bflo(wv[i]);
            a1 += bfhi(wv[i]);
        }
    }
    for (; p < end; p += 2) {
        int s0 = csr_src[p];
        unsigned int w0 = *reinterpret_cast<const unsigned int*>(
            h1b + (size_t)s0 * HDIM + 2 * c);
        a0 += bflo(w0);
        a1 += bfhi(w0);
    }
    a0 += __shfl_xor(a0, 32);
    a1 += __shfl_xor(a1, 32);
    // fused layer 2: t = relu(agg*dd + b1); p[j] = t @ W2 (partial, 2 feats)
    float t0 = a0 * dd + sB1[2 * c];
    float t1 = a1 * dd + sB1[2 * c + 1];
    t0 = t0 > 0.f ? t0 : 0.f;
    t1 = t1 > 0.f ? t1 : 0.f;
    float pj[CDIM];
#pragma unroll
    for (int j = 0; j < CDIM; ++j)
        pj[j] = t0 * sW2[(2 * c) * CDIM + j] + t1 * sW2[(2 * c + 1) * CDIM + j];
#pragma unroll
    for (int off = 1; off < 32; off <<= 1) {
#pragma unroll
        for (int j = 0; j < CDIM; ++j) pj[j] += __shfl_xor(pj[j], off);
    }
    if (lane < CDIM) {  // lanes 0..9 (half==0), c==lane
        float v = pj[0];
#pragma unroll
        for (int j = 1; j < CDIM; ++j)
            if (lane == j) v = pj[j];
        h2s[(size_t)node * H2LD + lane] = v * dd;
    }
}

// ---------------------------------------------------------------------------
// Stage 7: gather layer 2.  Wave per node, 4 groups x 16 lanes, 4 edges in
// flight per group; h2s rows 64-B aligned; shfl reduce; bias + self at end.
// ---------------------------------------------------------------------------
__global__ __launch_bounds__(256) void gather2_kernel(
        const int* __restrict__ row_ptr, const int* __restrict__ blk_sum,
        const int* __restrict__ csr_src, const float* __restrict__ dis,
        const float* __restrict__ h2s, const float* __restrict__ b2,
        float* __restrict__ out, int N) {
    int nid = blockIdx.x * 4 + (threadIdx.x >> 6);
    if (nid >= N) return;
    int node = __builtin_amdgcn_readfirstlane(nid);
    int lane = threadIdx.x & 63;
    int g = lane >> 4;
    int j = lane & 15;
    int beg = row_ptr[node] + blk_sum[node >> 10];
    int end = row_ptr[node + 1] + blk_sum[(node + 1) >> 10];
    float acc = 0.f;
    int p = beg + g;
    for (; p + 12 < end; p += 16) {  // 4 edges in flight per group
        int s0 = csr_src[p];
        int s1 = csr_src[p + 4];
        int s2 = csr_src[p + 8];
        int s3 = csr_src[p + 12];
        float v0 = (j < CDIM) ? h2s[(size_t)s0 * H2LD + j] : 0.f;
        float v1 = (j < CDIM) ? h2s[(size_t)s1 * H2LD + j] : 0.f;
        float v2 = (j < CDIM) ? h2s[(size_t)s2 * H2LD + j] : 0.f;
        float v3 = (j < CDIM) ? h2s[(size_t)s3 * H2LD + j] : 0.f;
        acc += (v0 + v1) + (v2 + v3);
    }
    for (; p < end; p += 4) {
        int s0 = csr_src[p];
        acc += (j < CDIM) ? h2s[(size_t)s0 * H2LD + j] : 0.f;
    }
    acc += __shfl_xor(acc, 16);
    acc += __shfl_xor(acc, 32);
    if (lane < CDIM) {
        float dd = dis[node];
        out[(size_t)node * CDIM + lane] =
            b2[lane] + dd * (acc + h2s[(size_t)node * H2LD + lane]);
    }
}

// ---------------------------------------------------------------------------
static inline char* align256(char* p) {
    return (char*)(((uintptr_t)p + 255) & ~(uintptr_t)255);
}

extern "C" void kernel_launch(void* const* d_in, const int* in_sizes, int n_in,
                              void* d_out, int out_size, void* d_ws,
                              size_t ws_size, hipStream_t stream) {
    const float* x  = (const float*)d_in[0];
    const int*   ei = (const int*)d_in[1];
    const float* W1 = (const float*)d_in[2];
    const float* b1 = (const float*)d_in[3];
    const float* W2 = (const float*)d_in[4];
    const float* b2 = (const float*)d_in[5];

    const int N = in_sizes[0] / F_IN;   // 100000
    const int E = in_sizes[1] / 2;      // 1600000
    const int* src = ei;
    const int* dst = ei + E;
    float* out = (float*)d_out;

    const int Np1 = N + 1;
    const int nscan_blocks = (Np1 + 1023) / 1024;

    // workspace layout, 256B-aligned chunks
    char* w = (char*)d_ws;
    int* deg = (int*)w;                  w = align256(w + (size_t)N * 4);  // zeroed
    char* zero_end = w;
    int* erank = (int*)w;                w = align256(w + (size_t)E * 4);
    float* dis = (float*)w;              w = align256(w + (size_t)N * 4);
    int* row_ptr = (int*)w;              w = align256(w + (size_t)(N + 4) * 4);
    int* blk_sum = (int*)w;              w = align256(w + (size_t)nscan_blocks * 4);
    int* csr_src = (int*)w;              w = align256(w + (size_t)E * 4);
    unsigned short* whf = (unsigned short*)w;  w = align256(w + (size_t)KPAD * HDIM * 2);
    unsigned short* wlf = (unsigned short*)w;  w = align256(w + (size_t)KPAD * HDIM * 2);
    unsigned short* h1b = (unsigned short*)w;  w = align256(w + (size_t)N * HDIM * 2);
    float* h2s = (float*)w;              w = align256(w + (size_t)N * H2LD * 4);

    hipMemsetAsync(deg, 0, (size_t)(zero_end - (char*)deg), stream);  // deg only

    const int degB = (E + 255) / 256;                    // 6250
    const int wprepB = (KPAD * HDIM + 255) / 256;        // 128
    prep_kernel<<<degB + wprepB, 256, 0, stream>>>(dst, E, deg, erank, W1, whf,
                                                   wlf, degB);
    scan_block_kernel<<<nscan_blocks, 1024, 0, stream>>>(deg, row_ptr, blk_sum,
                                                         dis, Np1);
    scan_top_kernel<<<1, 64, 0, stream>>>(blk_sum, nscan_blocks);
    {
        int gemmB = (N + 127) / 128;                     // 782
        int csrB = (E + 255) / 256;                      // 6250
        csr_gemm_kernel<<<gemmB + csrB, 256, 0, stream>>>(
            x, whf, wlf, dis, h1b, N,
            src, dst, erank, row_ptr, blk_sum, csr_src, E, gemmB);
    }
    gather1_l2_kernel<<<(N + 3) / 4, 256, 0, stream>>>(row_ptr, blk_sum,
                                                       csr_src, dis, h1b,
                                                       b1, W2, h2s, N);
    gather2_kernel<<<(N + 3) / 4, 256, 0, stream>>>(row_ptr, blk_sum, csr_src,
                                                    dis, h2s, b2, out, N);
}

// Round 5
// 516.080 us; speedup vs baseline: 1.1377x; 1.0338x over previous
//
#include <hip/hip_runtime.h>

#define F_IN 500
#define HDIM 64
#define CDIM 10
#define KPAD 512           // K padded to 16 MFMA stages of 32
#define NSTAGE 16
#define H2LD 16            // padded h2s row stride (64 B lines)
#define BUFSZ 24576        // per pipeline buffer: x 16K + wh 4K + wl 4K

typedef __attribute__((ext_vector_type(8))) short bf16x8;
typedef __attribute__((ext_vector_type(4))) float floatx4;

// RNE fp32 -> bf16 bits
__device__ inline unsigned short f2bf(float f) {
    unsigned int u = __float_as_uint(f);
    u += 0x7fffu + ((u >> 16) & 1u);
    return (unsigned short)(u >> 16);
}
__device__ inline float bflo(unsigned int u) { return __uint_as_float(u << 16); }
__device__ inline float bfhi(unsigned int u) { return __uint_as_float(u & 0xffff0000u); }

// async global->LDS, 16 B per lane; LDS dest is wave-uniform base + lane*16
__device__ inline void gload16(const void* g, void* l) {
    __builtin_amdgcn_global_load_lds(
        (const __attribute__((address_space(1))) void*)g,
        (__attribute__((address_space(3))) void*)l, 16, 0, 0);
}

// split 8 fp32 (two float4) into truncated-bf16 hi + residual-bf16 lo
__device__ inline void split8(float4 a, float4 b, bf16x8& xh, bf16x8& xl) {
    float xv[8] = {a.x, a.y, a.z, a.w, b.x, b.y, b.z, b.w};
#pragma unroll
    for (int j = 0; j < 8; ++j) {
        unsigned int u = __float_as_uint(xv[j]);
        xh[j] = (short)(u >> 16);
        float r = xv[j] - __uint_as_float(u & 0xffff0000u);
        xl[j] = (short)(__float_as_uint(r) >> 16);
    }
}

// ---------------------------------------------------------------------------
// Fused Stage 1: blocks [0, degB): in-degree histogram; the returned old
// value IS the edge's rank within its dst row -> erank.  Blocks [degB, ..):
// W1 split into trunc-bf16 hi + residual in MFMA B-fragment order.
// ---------------------------------------------------------------------------
__global__ __launch_bounds__(256) void prep_kernel(
        const int* __restrict__ dst, int E, int* __restrict__ deg,
        int* __restrict__ erank,
        const float* __restrict__ W1, unsigned short* __restrict__ whf,
        unsigned short* __restrict__ wlf, int degB) {
    int bid = blockIdx.x;
    if (bid < degB) {
        int e = bid * 256 + threadIdx.x;
        if (e < E) erank[e] = atomicAdd(&deg[dst[e]], 1);
    } else {
        int idx = (bid - degB) * 256 + threadIdx.x;  // over KPAD*HDIM
        if (idx >= KPAD * HDIM) return;
        int k = idx >> 6;
        int f = idx & 63;
        float w = (k < F_IN) ? W1[k * HDIM + f] : 0.f;
        unsigned int b = __float_as_uint(w);
        unsigned short hh = (unsigned short)(b >> 16);
        float wl = w - __uint_as_float(b & 0xffff0000u);
        unsigned short ll = (unsigned short)(__float_as_uint(wl) >> 16);
        int kb = k >> 5, q = (k >> 3) & 3, j = k & 7;
        int fb = f >> 4, fl = f & 15;
        int lane = (q << 4) | fl;
        size_t o = ((((size_t)kb * 4 + fb) * 64 + lane) << 3) | (size_t)j;
        whf[o] = hh;
        wlf[o] = ll;
    }
}

// ---------------------------------------------------------------------------
// Stage 2: per-block exclusive scan deg -> row_ptr partials; dis fused.
// ---------------------------------------------------------------------------
__global__ void scan_block_kernel(const int* __restrict__ deg,
                                  int* __restrict__ row_ptr,
                                  int* __restrict__ blk_sum,
                                  float* __restrict__ dis, int Np1) {
    __shared__ int wsum[16];
    int i = blockIdx.x * 1024 + threadIdx.x;
    int v = (i < Np1 - 1) ? deg[i] : 0;
    if (i < Np1 - 1) dis[i] = rsqrtf((float)(v + 1));
    int lane = threadIdx.x & 63;
    int wid = threadIdx.x >> 6;
    int x = v;
#pragma unroll
    for (int off = 1; off < 64; off <<= 1) {
        int y = __shfl_up(x, off);
        if (lane >= off) x += y;
    }
    if (lane == 63) wsum[wid] = x;
    __syncthreads();
    if (threadIdx.x < 16) {
        int ws = wsum[threadIdx.x];
#pragma unroll
        for (int off = 1; off < 16; off <<= 1) {
            int y = __shfl_up(ws, off);
            if ((int)threadIdx.x >= off) ws += y;
        }
        wsum[threadIdx.x] = ws;
    }
    __syncthreads();
    int wp = (wid > 0) ? wsum[wid - 1] : 0;
    if (i < Np1) row_ptr[i] = wp + x - v;
    if (threadIdx.x == 1023) blk_sum[blockIdx.x] = wp + x;
}

__global__ void scan_top_kernel(int* __restrict__ blk_sum, int nb) {
    int carry = 0;
    for (int base = 0; base < nb; base += 64) {
        int i = base + (int)threadIdx.x;
        int v = (i < nb) ? blk_sum[i] : 0;
        int x = v;
#pragma unroll
        for (int off = 1; off < 64; off <<= 1) {
            int y = __shfl_up(x, off);
            if ((int)threadIdx.x >= off) x += y;
        }
        if (i < nb) blk_sum[i] = carry + x - v;
        carry += __shfl(x, 63);
    }
}

// ---------------------------------------------------------------------------
// Fused Stage 3+4, INTERLEAVED: every 9th block runs the LDS-staged MFMA
// GEMM (BM=128 rows, 4 waves x 32 rows); others run the atomic-free CSR
// scatter.  GEMM K-loop: 2-phase double-buffered global_load_lds pipeline.
// x tile stored with XOR granule swizzle (applied on the per-lane GLOBAL
// source address; LDS dest linear).
// ---------------------------------------------------------------------------
__global__ __launch_bounds__(256) void csr_gemm_kernel(
        // gemm args
        const float* __restrict__ x, const unsigned short* __restrict__ whf,
        const unsigned short* __restrict__ wlf, const float* __restrict__ dis,
        unsigned short* __restrict__ h1b, int N,
        // csr args
        const int* __restrict__ src, const int* __restrict__ dst,
        const int* __restrict__ erank,
        const int* __restrict__ row_ptr, const int* __restrict__ blk_sum,
        int* __restrict__ csr_src, int E,
        int gemmB) {
    __shared__ float4 shmem[2 * BUFSZ / 16];
    char* sh = (char*)shmem;
    const int bid = blockIdx.x;
    const int g9 = bid / 9;
    const bool isGemm = (bid % 9 == 0) && (g9 < gemmB);
    if (!isGemm) {
        // ----- CSR fill path (no atomics: rank precomputed in prep) -----
        int before = (bid + 8) / 9;          // gemm blocks preceding bid
        if (before > gemmB) before = gemmB;
        int cb = bid - before;
        int e = cb * 256 + threadIdx.x;
        if (e >= E) return;
        int d = dst[e];
        csr_src[row_ptr[d] + blk_sum[d >> 10] + erank[e]] = src[e];
        return;
    }
    // ----- GEMM path: block tile 128 rows, wave handles 32 rows -----
    const int lane = threadIdx.x & 63;
    const int w = threadIdx.x >> 6;       // wave 0..3
    const int n0 = g9 * 128;
    const int q = lane >> 4;
    const int fl = lane & 15;

    floatx4 acc[2][4];
#pragma unroll
    for (int t = 0; t < 2; ++t)
#pragma unroll
        for (int fb = 0; fb < 4; ++fb) acc[t][fb] = (floatx4){0.f, 0.f, 0.f, 0.f};

    auto STAGE = [&](int buf, int kb) {
        const size_t bb = (size_t)buf * BUFSZ;
#pragma unroll
        for (int r2 = 0; r2 < 4; ++r2) {
            int c = w * 4 + r2;                 // 1 KiB chunk id, 0..15
            int o = c * 1024 + lane * 16;       // LDS byte offset in x region
            int ro = o >> 7;                    // tile row 0..127
            int gl = ((o >> 4) & 7) ^ (ro & 7); // logical granule for this slot
            if (kb == NSTAGE - 1 && gl > 4) gl = 0;  // k>=500 dead (w pad = 0)
            int xrow = n0 + ro;
            if (xrow >= N) xrow = N - 1;        // clamp (results discarded)
            gload16(x + (size_t)xrow * F_IN + kb * 32 + gl * 4,
                    sh + bb + c * 1024);
        }
        gload16((const char*)whf + (size_t)kb * 4096 + w * 1024 + lane * 16,
                sh + bb + 16384 + w * 1024);
        gload16((const char*)wlf + (size_t)kb * 4096 + w * 1024 + lane * 16,
                sh + bb + 20480 + w * 1024);
    };

    STAGE(0, 0);
    __syncthreads();
    int cur = 0;
#pragma unroll
    for (int kb = 0; kb < NSTAGE; ++kb) {
        if (kb + 1 < NSTAGE) STAGE(cur ^ 1, kb + 1);
        const size_t bb = (size_t)cur * BUFSZ;
        bf16x8 bh[4], bl[4];
#pragma unroll
        for (int fb = 0; fb < 4; ++fb) {
            bh[fb] = *(const bf16x8*)(sh + bb + 16384 + fb * 1024 + lane * 16);
            bl[fb] = *(const bf16x8*)(sh + bb + 20480 + fb * 1024 + lane * 16);
        }
#pragma unroll
        for (int t = 0; t < 2; ++t) {
            int tr = w * 32 + t * 16 + fl;      // tile row this lane reads
            int sw = tr & 7;
            float4 a0 = *(const float4*)(sh + bb + tr * 128 + (((2 * q) ^ sw) << 4));
            float4 a1 = *(const float4*)(sh + bb + tr * 128 + (((2 * q + 1) ^ sw) << 4));
            bf16x8 xh, xl;
            split8(a0, a1, xh, xl);
#pragma unroll
            for (int fb = 0; fb < 4; ++fb) {
                acc[t][fb] = __builtin_amdgcn_mfma_f32_16x16x32_bf16(xh, bh[fb], acc[t][fb], 0, 0, 0);
                acc[t][fb] = __builtin_amdgcn_mfma_f32_16x16x32_bf16(xl, bh[fb], acc[t][fb], 0, 0, 0);
                acc[t][fb] = __builtin_amdgcn_mfma_f32_16x16x32_bf16(xh, bl[fb], acc[t][fb], 0, 0, 0);
            }
        }
        __syncthreads();   // drains vmcnt (next stage ready) + lgkm (reads done)
        cur ^= 1;
    }
    // epilogue: C/D layout row = q*4+r, col = fb*16+fl
#pragma unroll
    for (int t = 0; t < 2; ++t) {
#pragma unroll
        for (int r = 0; r < 4; ++r) {
            int node = n0 + w * 32 + t * 16 + q * 4 + r;
            if (node < N) {
                float dn = dis[node];
#pragma unroll
                for (int fb = 0; fb < 4; ++fb) {
                    h1b[(size_t)node * HDIM + fb * 16 + fl] =
                        f2bf(acc[t][fb][r] * dn);
                }
            }
        }
    }
}

// ---------------------------------------------------------------------------
// Stage 5+6 fused: gather layer 1 + layer-2 dense, full-node MLP version.
// Wave per node.  Edge list loaded with ONE coalesced read (lane i <-
// csr_src[beg+i]); indices distributed by __shfl.  ALL __shfl calls execute
// at FULL wave exec (uniform loop bounds; parity folded into the per-lane
// idx; only the gather LOAD is predicated) -- ds_bpermute from an
// exec-inactive source lane is undefined, which was round 3's bug.
// 16 gathers in flight per half-wave.  Tail: in-register relu+b1 and 64x10
// matvec via shfl reduce; h2s written directly.
// ---------------------------------------------------------------------------
__global__ __launch_bounds__(256) void gather1_l2_kernel(
        const int* __restrict__ row_ptr, const int* __restrict__ blk_sum,
        const int* __restrict__ csr_src, const float* __restrict__ dis,
        const unsigned short* __restrict__ h1b,
        const float* __restrict__ b1, const float* __restrict__ W2,
        float* __restrict__ h2s, int N) {
    __shared__ float sW2[HDIM * CDIM];
    __shared__ float sB1[HDIM];
    for (int i = threadIdx.x; i < HDIM * CDIM; i += 256) sW2[i] = W2[i];
    if (threadIdx.x < HDIM) sB1[threadIdx.x] = b1[threadIdx.x];
    __syncthreads();
    int nid = blockIdx.x * 4 + (threadIdx.x >> 6);
    if (nid >= N) return;
    int node = __builtin_amdgcn_readfirstlane(nid);
    int lane = threadIdx.x & 63;
    int half = lane >> 5;
    int c = lane & 31;  // features 2c, 2c+1
    int beg = row_ptr[node] + blk_sum[node >> 10];
    int end = row_ptr[node + 1] + blk_sum[(node + 1) >> 10];
    int deg = end - beg;
    float dd = dis[node];
    float a0 = 0.f, a1 = 0.f;
    if (half == 0) {  // self-loop: row already holds h1*dis[node]
        unsigned int w = *reinterpret_cast<const unsigned int*>(
            h1b + (size_t)node * HDIM + 2 * c);
        a0 = bflo(w);
        a1 = bfhi(w);
    }
    for (int base = 0; base < deg; base += 64) {
        int cnt = deg - base;
        if (cnt > 64) cnt = 64;
        int eidx = 0;                           // default -> safe node 0
        if (base + lane < deg) eidx = csr_src[beg + base + lane];
        for (int i0 = 0; i0 < cnt; i0 += 32) {  // wave-uniform trip count
            unsigned int wv[16];
#pragma unroll
            for (int u = 0; u < 16; ++u) {
                int idx = i0 + 2 * u + half;    // half0 evens, half1 odds; <=63
                int s = __shfl(eidx, idx);      // FULL-exec shfl, sources defined
                unsigned int v = 0;
                if (idx < cnt)
                    v = *reinterpret_cast<const unsigned int*>(
                        h1b + (size_t)s * HDIM + 2 * c);
                wv[u] = v;
            }
#pragma unroll
            for (int u = 0; u < 16; ++u) {
                a0 += bflo(wv[u]);
                a1 += bfhi(wv[u]);
            }
        }
    }
    a0 += __shfl_xor(a0, 32);
    a1 += __shfl_xor(a1, 32);
    // fused layer 2: t = relu(agg*dd + b1); p[j] = t @ W2 (partial, 2 feats)
    float t0 = a0 * dd + sB1[2 * c];
    float t1 = a1 * dd + sB1[2 * c + 1];
    t0 = t0 > 0.f ? t0 : 0.f;
    t1 = t1 > 0.f ? t1 : 0.f;
    float pj[CDIM];
#pragma unroll
    for (int j = 0; j < CDIM; ++j)
        pj[j] = t0 * sW2[(2 * c) * CDIM + j] + t1 * sW2[(2 * c + 1) * CDIM + j];
#pragma unroll
    for (int off = 1; off < 32; off <<= 1) {
#pragma unroll
        for (int j = 0; j < CDIM; ++j) pj[j] += __shfl_xor(pj[j], off);
    }
    if (lane < CDIM) {  // lanes 0..9 (half==0), c==lane
        float v = pj[0];
#pragma unroll
        for (int j = 1; j < CDIM; ++j)
            if (lane == j) v = pj[j];
        h2s[(size_t)node * H2LD + lane] = v * dd;
    }
}

// ---------------------------------------------------------------------------
// Stage 7: gather layer 2, full-node MLP version.  Wave per node, 4 groups
// x 16 lanes; edge list via one coalesced load + full-exec shfl; 8-deep
// predicated loads per group (32 edges in flight per wave).
// ---------------------------------------------------------------------------
__global__ __launch_bounds__(256) void gather2_kernel(
        const int* __restrict__ row_ptr, const int* __restrict__ blk_sum,
        const int* __restrict__ csr_src, const float* __restrict__ dis,
        const float* __restrict__ h2s, const float* __restrict__ b2,
        float* __restrict__ out, int N) {
    int nid = blockIdx.x * 4 + (threadIdx.x >> 6);
    if (nid >= N) return;
    int node = __builtin_amdgcn_readfirstlane(nid);
    int lane = threadIdx.x & 63;
    int g = lane >> 4;
    int j = lane & 15;
    int beg = row_ptr[node] + blk_sum[node >> 10];
    int end = row_ptr[node + 1] + blk_sum[(node + 1) >> 10];
    int deg = end - beg;
    float acc = 0.f;
    for (int base = 0; base < deg; base += 64) {
        int cnt = deg - base;
        if (cnt > 64) cnt = 64;
        int eidx = 0;                           // default -> safe node 0
        if (base + lane < deg) eidx = csr_src[beg + base + lane];
        for (int i0 = 0; i0 < cnt; i0 += 32) {  // wave-uniform trip count
            float v[8];
#pragma unroll
            for (int u = 0; u < 8; ++u) {
                int idx = i0 + 4 * u + g;       // group g: idx ≡ g (mod 4); <=63
                int s = __shfl(eidx, idx);      // FULL-exec shfl
                float vv = 0.f;
                if (idx < cnt && j < CDIM) vv = h2s[(size_t)s * H2LD + j];
                v[u] = vv;
            }
#pragma unroll
            for (int u = 0; u < 8; ++u) acc += v[u];
        }
    }
    acc += __shfl_xor(acc, 16);
    acc += __shfl_xor(acc, 32);
    if (lane < CDIM) {
        float dd = dis[node];
        out[(size_t)node * CDIM + lane] =
            b2[lane] + dd * (acc + h2s[(size_t)node * H2LD + lane]);
    }
}

// ---------------------------------------------------------------------------
static inline char* align256(char* p) {
    return (char*)(((uintptr_t)p + 255) & ~(uintptr_t)255);
}

extern "C" void kernel_launch(void* const* d_in, const int* in_sizes, int n_in,
                              void* d_out, int out_size, void* d_ws,
                              size_t ws_size, hipStream_t stream) {
    const float* x  = (const float*)d_in[0];
    const int*   ei = (const int*)d_in[1];
    const float* W1 = (const float*)d_in[2];
    const float* b1 = (const float*)d_in[3];
    const float* W2 = (const float*)d_in[4];
    const float* b2 = (const float*)d_in[5];

    const int N = in_sizes[0] / F_IN;   // 100000
    const int E = in_sizes[1] / 2;      // 1600000
    const int* src = ei;
    const int* dst = ei + E;
    float* out = (float*)d_out;

    const int Np1 = N + 1;
    const int nscan_blocks = (Np1 + 1023) / 1024;

    // workspace layout, 256B-aligned chunks
    char* w = (char*)d_ws;
    int* deg = (int*)w;                  w = align256(w + (size_t)N * 4);  // zeroed
    char* zero_end = w;
    int* erank = (int*)w;                w = align256(w + (size_t)E * 4);
    float* dis = (float*)w;              w = align256(w + (size_t)N * 4);
    int* row_ptr = (int*)w;              w = align256(w + (size_t)(N + 4) * 4);
    int* blk_sum = (int*)w;              w = align256(w + (size_t)nscan_blocks * 4);
    int* csr_src = (int*)w;              w = align256(w + (size_t)E * 4);
    unsigned short* whf = (unsigned short*)w;  w = align256(w + (size_t)KPAD * HDIM * 2);
    unsigned short* wlf = (unsigned short*)w;  w = align256(w + (size_t)KPAD * HDIM * 2);
    unsigned short* h1b = (unsigned short*)w;  w = align256(w + (size_t)N * HDIM * 2);
    float* h2s = (float*)w;              w = align256(w + (size_t)N * H2LD * 4);

    hipMemsetAsync(deg, 0, (size_t)(zero_end - (char*)deg), stream);  // deg only

    const int degB = (E + 255) / 256;                    // 6250
    const int wprepB = (KPAD * HDIM + 255) / 256;        // 128
    prep_kernel<<<degB + wprepB, 256, 0, stream>>>(dst, E, deg, erank, W1, whf,
                                                   wlf, degB);
    scan_block_kernel<<<nscan_blocks, 1024, 0, stream>>>(deg, row_ptr, blk_sum,
                                                         dis, Np1);
    scan_top_kernel<<<1, 64, 0, stream>>>(blk_sum, nscan_blocks);
    {
        int gemmB = (N + 127) / 128;                     // 782
        int csrB = (E + 255) / 256;                      // 6250
        csr_gemm_kernel<<<gemmB + csrB, 256, 0, stream>>>(
            x, whf, wlf, dis, h1b, N,
            src, dst, erank, row_ptr, blk_sum, csr_src, E, gemmB);
    }
    gather1_l2_kernel<<<(N + 3) / 4, 256, 0, stream>>>(row_ptr, blk_sum,
                                                       csr_src, dis, h1b,
                                                       b1, W2, h2s, N);
    gather2_kernel<<<(N + 3) / 4, 256, 0, stream>>>(row_ptr, blk_sum, csr_src,
                                                    dis, h2s, b2, out, N);
}